// Round 6
// baseline (379.847 us; speedup 1.0000x reference)
//
#include <hip/hip_runtime.h>

// EdgeBlock: out = relu(concat(xn[src], xn[dst], xe) @ W1 + b1) @ W2 + b2
// R4: BM=64, 256 threads (4 waves), LDS 72KB -> 2 blocks/CU for inter-block
// latency hiding; shfl-paired u32 Hs writes (kill bank conflicts); gload_lds
// staging; 2-phase dbuf; coalesced LDS-staged f32 output.

typedef __attribute__((ext_vector_type(8))) short short8;   // MFMA A/B frag (8 bf16)
typedef __attribute__((ext_vector_type(4))) float f32x4;    // MFMA C/D frag

typedef __attribute__((address_space(1))) unsigned int* gp1_t;
typedef __attribute__((address_space(3))) unsigned int* lp3_t;

#define AS_OFF 0         // As: 2 x 4KB  (64 rows x 64B)
#define BS_OFF 8192      // Bs: 2 x 16KB (256 rows x 64B)
#define HS_OFF 40960     // Hs: 32KB     (64 rows x 512B, chunk-swizzled)
#define SMEM_SZ 73728    // 72KB -> 2 blocks/CU
#define LDO 260          // f32 out-stage row stride (256+4 pad)

__device__ __forceinline__ unsigned short f2b(float f) {
  unsigned int u = __float_as_uint(f);
  return (unsigned short)((u + 0x7FFFu + ((u >> 16) & 1u)) >> 16);
}
__device__ __forceinline__ unsigned int f2b2(float lo, float hi) {
  return (unsigned int)f2b(lo) | ((unsigned int)f2b(hi) << 16);
}
__device__ __forceinline__ void gload16(const void* g, void* l) {
  __builtin_amdgcn_global_load_lds((gp1_t)g, (lp3_t)l, 16, 0, 0);
}

// Pack W[k][256] -> wp[kc][n][kin] bf16 (chunk kc = 32 k-rows, contiguous 16KB)
__global__ void prep_w_kernel(const float* __restrict__ w,
                              unsigned short* __restrict__ wp, int total) {
  int i = blockIdx.x * 256 + threadIdx.x;
  if (i >= total) return;
  int kc = i >> 13;          // 8192 elems per chunk
  int rem = i & 8191;
  int n = rem >> 5;
  int kin = rem & 31;
  wp[i] = f2b(w[(size_t)(kc * 32 + kin) * 256 + n]);
}

__global__ void conv_bf16_kernel(const float* __restrict__ x,
                                 unsigned short* __restrict__ y, int n4) {
  int i = blockIdx.x * 256 + threadIdx.x;
  if (i >= n4) return;
  float4 v = ((const float4*)x)[i];
  ushort4 u;
  u.x = f2b(v.x); u.y = f2b(v.y); u.z = f2b(v.z); u.w = f2b(v.w);
  ((ushort4*)y)[i] = u;
}

__global__ __launch_bounds__(256, 2) void edge_mlp_kernel(
    const float* __restrict__ xnode, const float* __restrict__ xedge,
    const int* __restrict__ eidx,
    const unsigned short* __restrict__ nodeb, int use_nodeb,
    const unsigned short* __restrict__ wt1p, const float* __restrict__ b1,
    const unsigned short* __restrict__ wt2p, const float* __restrict__ b2,
    float* __restrict__ out, int E) {
  __shared__ __align__(16) char smem[SMEM_SZ];
  char* As = smem + AS_OFF;
  char* Bs = smem + BS_OFF;
  char* Hs = smem + HS_OFF;

  const int t = threadIdx.x;
  const int w = t >> 6, l = t & 63;
  const int lr = l & 15, lk = l >> 4;
  // wave grid 1(M) x 4(N): wave w -> cols [64w, 64w+64), rows 0..63
  const int row4 = t >> 2;               // staging row 0..63
  const int c4 = t & 3;                  // staging 16B-chunk in row

  const int ebase = blockIdx.x * 64;
  int e = ebase + row4;
  if (e >= E) e = E - 1;                 // clamp tail; stores guarded
  const int isrc = eidx[e], idst = eidx[E + e];

  f32x4 acc[4][4];
#pragma unroll
  for (int i = 0; i < 4; ++i)
#pragma unroll
    for (int j = 0; j < 4; ++j) acc[i][j] = (f32x4)0.0f;

  // --- staging helpers ---
  // B chunk: 16KB linear from pre-packed weights (4 x gload16 per thread)
  auto stageB = [&](const unsigned short* wp, int kc, int buf) {
    const char* g = (const char*)wp + (size_t)kc * 16384 + t * 16;
    char* lb = Bs + buf * 16384 + (w << 10);       // wave-uniform base
#pragma unroll
    for (int q = 0; q < 4; ++q) gload16(g + q * 4096, lb + q * 4096);
  };
  // A node chunk: gathered bf16 rows, per-lane global addr, linear LDS dest
  auto stageA_node = [&](int kc, int buf) {
    const int node = (kc < 8) ? isrc : idst;
    const char* g = (const char*)nodeb + (size_t)node * 512 + (kc & 7) * 64 + c4 * 16;
    gload16(g, As + buf * 4096 + (w << 10));
  };
  // manual path (f32 source): issue loads early ...
  auto stageA_load = [&](int kc, float4& m0, float4& m1) {
    const float* src;
    if (kc < 8)        src = xnode + (size_t)isrc * 256 + kc * 32 + c4 * 8;
    else if (kc < 16)  src = xnode + (size_t)idst * 256 + (kc - 8) * 32 + c4 * 8;
    else               src = xedge + (size_t)e * 256 + (kc - 16) * 32 + c4 * 8;
    m0 = *(const float4*)src;
    m1 = *(const float4*)(src + 4);
  };
  // ... convert+write late (after compute), T14 split
  auto stageA_write = [&](int buf, float4 m0, float4 m1) {
    uint4 u;
    u.x = f2b2(m0.x, m0.y); u.y = f2b2(m0.z, m0.w);
    u.z = f2b2(m1.x, m1.y); u.w = f2b2(m1.z, m1.w);
    *(uint4*)(As + buf * 4096 + t * 16) = u;
  };

  auto compute1 = [&](int buf) {
    short8 af[4], bf[4];
    const char* ab = As + buf * 4096;
    const char* bb = Bs + buf * 16384;
#pragma unroll
    for (int mi = 0; mi < 4; ++mi)
      af[mi] = *(const short8*)(ab + (mi * 16 + lr) * 64 + lk * 16);
#pragma unroll
    for (int ni = 0; ni < 4; ++ni)
      bf[ni] = *(const short8*)(bb + (w * 64 + ni * 16 + lr) * 64 + lk * 16);
#pragma unroll
    for (int mi = 0; mi < 4; ++mi)
#pragma unroll
      for (int ni = 0; ni < 4; ++ni)
        acc[mi][ni] = __builtin_amdgcn_mfma_f32_16x16x32_bf16(
            af[mi], bf[ni], acc[mi][ni], 0, 0, 0);
  };

  // ---------------- GEMM1: 24 chunks of K=32, 2-phase dbuf ----------------
  stageB(wt1p, 0, 0);
  if (use_nodeb) {
    stageA_node(0, 0);
  } else {
    float4 a0, a1;
    stageA_load(0, a0, a1);
    stageA_write(0, a0, a1);
  }
  __syncthreads();

  for (int kc = 0; kc < 24; ++kc) {
    const int cur = kc & 1, nb = cur ^ 1;
    float4 m0, m1;
    bool man = false;
    if (kc < 23) {
      const int nk = kc + 1;
      stageB(wt1p, nk, nb);
      if (use_nodeb && nk < 16) {
        stageA_node(nk, nb);
      } else {
        stageA_load(nk, m0, m1);
        man = true;
      }
    } else {
      stageB(wt2p, 0, nb);   // prefetch W2 chunk 0 across the boundary
    }
    compute1(cur);
    if (man) stageA_write(nb, m0, m1);
    __syncthreads();
  }

  // ------- bias + ReLU -> Hs (bf16, chunk-swizzled, shfl-paired u32 writes) -------
#pragma unroll
  for (int ni = 0; ni < 4; ++ni) {
    const int col = w * 64 + ni * 16 + lr;
    const float bias = b1[col];
    const int cole = col & ~1;
    const int chunk = cole >> 3;
    const int cb = (cole & 6) * 2;     // byte offset within 16B chunk (4B aligned)
#pragma unroll
    for (int mi = 0; mi < 4; ++mi) {
      float v[4], p[4];
#pragma unroll
      for (int r = 0; r < 4; ++r) {
        float x = acc[mi][ni][r] + bias;
        v[r] = x > 0.f ? x : 0.f;
        acc[mi][ni][r] = 0.f;          // reset for GEMM2
      }
#pragma unroll
      for (int r = 0; r < 4; ++r) p[r] = __shfl_xor(v[r], 1, 64);
      const int r0 = (lr & 1) ? 2 : 0; // even lane: rows r=0,1; odd: r=2,3
#pragma unroll
      for (int rr = 0; rr < 2; ++rr) {
        const int r = r0 + rr;
        const int row = mi * 16 + lk * 4 + r;
        const float lo = (lr & 1) ? p[r] : v[r];
        const float hi = (lr & 1) ? v[r] : p[r];
        *(unsigned int*)(Hs + row * 512 + ((chunk ^ (row & 7)) << 4) + cb) = f2b2(lo, hi);
      }
    }
  }
  __syncthreads();

  // ---------------- GEMM2: 8 chunks of K=32, 2-phase dbuf ----------------
  for (int kc2 = 0; kc2 < 8; ++kc2) {
    const int cur = kc2 & 1, nb = cur ^ 1;
    if (kc2 < 7) stageB(wt2p, kc2 + 1, nb);
    {
      short8 af[4], bf[4];
      const char* bb = Bs + cur * 16384;
#pragma unroll
      for (int mi = 0; mi < 4; ++mi) {
        const int row = mi * 16 + lr;
        af[mi] = *(const short8*)(Hs + row * 512 + (((kc2 * 4 + lk) ^ (row & 7)) << 4));
      }
#pragma unroll
      for (int ni = 0; ni < 4; ++ni)
        bf[ni] = *(const short8*)(bb + (w * 64 + ni * 16 + lr) * 64 + lk * 16);
#pragma unroll
      for (int mi = 0; mi < 4; ++mi)
#pragma unroll
        for (int ni = 0; ni < 4; ++ni)
          acc[mi][ni] = __builtin_amdgcn_mfma_f32_16x16x32_bf16(
              af[mi], bf[ni], acc[mi][ni], 0, 0, 0);
    }
    __syncthreads();
  }

  // ---------------- bias + coalesced store via LDS f32 round-trip ----------------
  float* outst = (float*)smem;   // unions As+Bs+Hs (all dead after final sync)
#pragma unroll
  for (int ni = 0; ni < 4; ++ni) {
    const int col = w * 64 + ni * 16 + lr;
    const float bias = b2[col];
#pragma unroll
    for (int mi = 0; mi < 4; ++mi)
#pragma unroll
      for (int r = 0; r < 4; ++r)
        outst[(mi * 16 + lk * 4 + r) * LDO + col] = acc[mi][ni][r] + bias;
  }
  __syncthreads();
#pragma unroll
  for (int it = 0; it < 16; ++it) {
    const int idx = it * 1024 + t * 4;   // f32 index within 64x256 tile
    const int lrow = idx >> 8;
    const int cc = idx & 255;
    const int grow = ebase + lrow;
    if (grow < E)
      *(float4*)(out + (size_t)grow * 256 + cc) =
          *(const float4*)(outst + lrow * LDO + cc);
  }
}

extern "C" void kernel_launch(void* const* d_in, const int* in_sizes, int n_in,
                              void* d_out, int out_size, void* d_ws, size_t ws_size,
                              hipStream_t stream) {
  const float* xnode = (const float*)d_in[0];
  const float* xedge = (const float*)d_in[1];
  const int* eidx = (const int*)d_in[2];
  const float* W1 = (const float*)d_in[3];
  const float* b1 = (const float*)d_in[4];
  const float* W2 = (const float*)d_in[5];
  const float* b2 = (const float*)d_in[6];
  float* out = (float*)d_out;

  const int NN = in_sizes[0] / 256;   // 50000
  const int E = in_sizes[1] / 256;    // 300000

  char* ws = (char*)d_ws;
  unsigned short* wt1p = (unsigned short*)ws;                       // 24 chunks = 384KB
  unsigned short* wt2p = (unsigned short*)(ws + 24 * 16384);        //  8 chunks = 128KB
  unsigned short* nodeb = (unsigned short*)(ws + 32 * 16384);       // NN*512B
  const size_t need = (size_t)32 * 16384 + (size_t)NN * 512;
  const int use_nodeb = (ws_size >= need) ? 1 : 0;

  prep_w_kernel<<<(24 * 8192 + 255) / 256, 256, 0, stream>>>(W1, wt1p, 24 * 8192);
  prep_w_kernel<<<(8 * 8192 + 255) / 256, 256, 0, stream>>>(W2, wt2p, 8 * 8192);
  if (use_nodeb) {
    const int n4 = NN * 64;
    conv_bf16_kernel<<<(n4 + 255) / 256, 256, 0, stream>>>(xnode, nodeb, n4);
  }

  edge_mlp_kernel<<<(E + 63) / 64, 256, 0, stream>>>(
      xnode, xedge, eidx, nodeb, use_nodeb, wt1p, b1, wt2p, b2, out, E);
}